// Round 6
// baseline (42.505 us; speedup 1.0000x reference)
//
#include <hip/hip_runtime.h>
#include <hip/hip_bf16.h>

#define LOG2E 1.44269504088896340736f
#define C2G   0.39894228040143267794f   // 1/sqrt(2*pi)
#define K2M  -0.79788456080286535588f   // -2*C2G

typedef __attribute__((ext_vector_type(4))) float f32x4;
typedef __attribute__((ext_vector_type(8))) short s16x8;
typedef __attribute__((ext_vector_type(4))) short s16x4;

// ---------------- workspace layout (float offsets) ----------------
// Only bf16 fragment arrays live in global scratch now.
static constexpr size_t QF_OFF  = 0;        // [4h][64nt][2s][64l][8j] bf16 = 262144 sh
static constexpr size_t KF_OFF  = 131072;   // same shape (m-tiles)
static constexpr size_t VF_OFF  = 262144;   // [32ks][8tc][64l][8j] bf16 = 131072 sh
static constexpr size_t WoF_OFF = 327680;   // [8ot][4s][64l][8j]  bf16 = 16384 sh
// total = 335,872 floats = 1.28 MB

__device__ __forceinline__ short f2bfs(float f){
    __hip_bfloat16 h = __float2bfloat16(f);
    return __builtin_bit_cast(short, h);
}

__device__ __forceinline__ float wave_sum64(float v){
    #pragma unroll
    for (int m = 32; m >= 1; m >>= 1) v += __shfl_xor(v, m, 64);
    return v;
}

// ---------------- kernel 1: projections + pos terms -> bf16 fragments ----
// grid (64, 4): x = n-tile of 16, y = mat (0=Q,1=K,2=V,3=pos/WoF)
// Fragment k-bijections (A and B use the SAME map; validated on HW round 5):
//   scores g(l,j) = (l>>4)*8 + j            (K=64 over 2 slots)
//   PV/Wo  f(l,j) = (l>>4)*4 + (j&3) + 16*(j>>2)
__global__ __launch_bounds__(256) void k_prep(
    const float* __restrict__ x, const float* __restrict__ xyz,
    const float* __restrict__ Wq, const float* __restrict__ Wk,
    const float* __restrict__ Wv, const float* __restrict__ Wp1,
    const float* __restrict__ bp1, const float* __restrict__ Wp2,
    const float* __restrict__ bp2, const float* __restrict__ Wo,
    float* __restrict__ ws)
{
    __shared__ float wlds[128*129];   // W [c][k] pitch 129 (mat3: scratch)
    __shared__ float xlds[128*16];    // x [k][n16]
    __shared__ float stage[128*17];   // output tile [c][n] pitch 17 (mat3: p-tile)
    const int t   = threadIdx.x;
    const int mat = blockIdx.y;
    const int bx  = blockIdx.x;
    const int n0  = bx * 16;
    const int l = t & 63, wv_ = t >> 6, g = l >> 4, col = l & 15;

    if (mat == 3){
        float* wb   = wlds;           // [4][128]
        float* Msh  = wlds + 512;     // [4][9]
        float* bbar = wlds + 548;     // [4]
        float* kg   = wlds + 552;     // [4][3][16]  K2M*(M_h·xyz[n])
        float* rowt = wlds + 744;     // [4][16]
        float* colt = wlds + 808;     // [4][16]
        float* pt   = stage;          // [128][17]

        for (int idx = t; idx < 512; idx += 256){
            const int h = idx >> 7, c = idx & 127;
            float s = 0.f;
            #pragma unroll 8
            for (int d = 0; d < 32; d++) s += Wp2[(size_t)(h*32+d)*128 + c];
            wb[idx] = s * 0.03125f;
        }
        if (t < 4){
            float s = 0.f;
            #pragma unroll 8
            for (int d = 0; d < 32; d++) s += bp2[t*32+d];
            bbar[t] = s * 0.03125f;
        }
        {   // p-tile
            const int c = t & 127, ng = t >> 7;
            const float w0 = Wp1[c*3], w1 = Wp1[c*3+1], w2 = Wp1[c*3+2];
            #pragma unroll
            for (int i = 0; i < 8; i++){
                const int nn = ng*8 + i, n = n0 + nn;
                pt[c*17 + nn] = w0*xyz[n*3] + w1*xyz[n*3+1] + w2*xyz[n*3+2];
            }
        }
        __syncthreads();

        if (t < 36){   // M_h[a][b] = sum_c wbar * Wp1[c,a] * Wp1[c,b]
            const int h = t / 9, ab = t % 9, a = ab / 3, b = ab % 3;
            float m = 0.f;
            for (int c = 0; c < 128; c++)
                m += wb[h*128+c] * Wp1[c*3+a] * Wp1[c*3+b];
            Msh[t] = m;
        }
        __syncthreads();

        if (t < 64){   // ROWT / COLT
            const int h = t >> 4, nn = t & 15;
            float ra = 0.f, ca = 0.f;
            for (int c = 0; c < 128; c++){
                const float w  = wb[h*128+c];
                const float p  = pt[c*17+nn];
                const float b1 = bp1[c];
                const float a  = fmaf(2.f*C2G, b1, 0.5f);
                const float p2 = C2G*p*p;
                ra += w * (a*p + p2 + 0.5f*b1 + C2G*b1*b1);
                ca += w * (p2 - a*p);
            }
            rowt[h*16+nn] = ra + bbar[h];
            colt[h*16+nn] = ca;
        } else if (t < 64 + 192){   // kg[h][a][nn]
            const int u = t - 64;
            const int nn = u & 15, ha = u >> 4, h = ha / 3, a = ha % 3;
            const int n = n0 + nn;
            const float gv = Msh[h*9+a*3+0]*xyz[n*3+0]
                           + Msh[h*9+a*3+1]*xyz[n*3+1]
                           + Msh[h*9+a*3+2]*xyz[n*3+2];
            kg[(h*3+a)*16 + nn] = K2M * gv;
        }
        __syncthreads();

        // emit bias fragments (s=1) for QF and KF: 8 slots, 2 per wave
        for (int sl = wv_; sl < 8; sl += 4){
            const bool isQ = sl < 4;
            const int  h   = sl & 3;
            s16x8 v;
            #pragma unroll
            for (int j = 0; j < 8; j++){
                const int dd = g*8 + j;
                float f;
                if (isQ)
                    f = (dd < 3)  ? kg[(h*3+dd)*16 + col]
                      : (dd == 3) ? rowt[h*16 + col]
                      : (dd == 4) ? 1.0f : 0.0f;
                else
                    f = (dd < 3)  ? xyz[(size_t)(n0+col)*3 + dd]
                      : (dd == 3) ? 1.0f
                      : (dd == 4) ? colt[h*16 + col] : 0.0f;
                v[j] = f2bfs(f);
            }
            ((s16x8*)(ws + (isQ ? QF_OFF : KF_OFF)))[(size_t)(h*128 + bx*2 + 1)*64 + l] = v;
        }

        // WoF: blocks bx<8, one slot per wave. slot = ot*4 + s.
        if (bx < 8){
            const int slot = bx*4 + wv_;
            const int ot = slot >> 2, s = slot & 3;
            s16x8 v;
            #pragma unroll
            for (int j = 0; j < 8; j++)
                v[j] = f2bfs(Wo[(size_t)(ot*16 + col)*128
                               + s*32 + g*4 + (j&3) + 16*(j>>2)]);
            ((s16x8*)(ws + WoF_OFF))[(size_t)slot*64 + l] = v;
        }
        return;
    }

    // ---- mats 0..2: GEMM tile + fragment emit ----
    const float* W = (mat == 0) ? Wq : (mat == 1 ? Wk : Wv);
    for (int i = t; i < 16384; i += 256)
        wlds[(i>>7)*129 + (i&127)] = W[i];
    for (int i = t; i < 2048; i += 256)
        xlds[i] = x[(size_t)(i>>4)*1024 + n0 + (i&15)];
    __syncthreads();

    const int c = t & 127, ng = t >> 7;
    float acc[8] = {0,0,0,0,0,0,0,0};
    #pragma unroll 4
    for (int k = 0; k < 128; k++){
        const float wv = wlds[c*129 + k];
        const float4 a0 = *(const float4*)&xlds[k*16 + ng*8];
        const float4 a1 = *(const float4*)&xlds[k*16 + ng*8 + 4];
        acc[0] = fmaf(wv, a0.x, acc[0]);
        acc[1] = fmaf(wv, a0.y, acc[1]);
        acc[2] = fmaf(wv, a0.z, acc[2]);
        acc[3] = fmaf(wv, a0.w, acc[3]);
        acc[4] = fmaf(wv, a1.x, acc[4]);
        acc[5] = fmaf(wv, a1.y, acc[5]);
        acc[6] = fmaf(wv, a1.z, acc[6]);
        acc[7] = fmaf(wv, a1.w, acc[7]);
    }
    const float qs = (mat == 0) ? 0.17677669529663689f : 1.0f;  // 1/sqrt(32)
    #pragma unroll
    for (int i = 0; i < 8; i++)
        stage[c*17 + ng*8 + i] = acc[i] * qs;
    __syncthreads();

    if (mat != 2){   // Q/K s=0 fragment: wave = head
        const int h = wv_;
        s16x8 v;
        #pragma unroll
        for (int j = 0; j < 8; j++)
            v[j] = f2bfs(stage[(h*32 + g*8 + j)*17 + col]);
        ((s16x8*)(ws + (mat == 0 ? QF_OFF : KF_OFF)))[(size_t)(h*128 + bx*2 + 0)*64 + l] = v;
    } else {         // V half-fragments: this block is m-tile bx
        #pragma unroll
        for (int q = 0; q < 2; q++){
            const int tc = wv_*2 + q;
            s16x4 hv;
            #pragma unroll
            for (int jj = 0; jj < 4; jj++)
                hv[jj] = f2bfs(stage[(tc*16 + col)*17 + g*4 + jj]);
            ((s16x4*)(ws + VF_OFF))[(((size_t)(bx>>1)*8 + tc)*64 + l)*2 + (bx & 1)] = hv;
        }
    }
}

// ---------------- kernel 2: flash attention + Wo + residual + LN --------
// grid (64): n-tile of 16. block 256 = 4 waves, wave = head.
__global__ __launch_bounds__(256) void k_fused(
    const float* __restrict__ bo, const float* __restrict__ x,
    const float* __restrict__ gamma, const float* __restrict__ beta,
    const float* __restrict__ ws_c, float* __restrict__ out)
{
    __shared__ float red[4*8*64*4];   // [h][ot][l][4]  Wo partials (32 KB)
    __shared__ float lds2[16*128];    // [n][o] pre-LN tile
    __shared__ float stats[32];       // mu[16], rstd[16]

    const int t = threadIdx.x, l = t & 63, h = t >> 6;
    const int g = l >> 4, col = l & 15;
    const int bx = blockIdx.x, n0 = bx*16;

    const s16x8* QFv  = (const s16x8*)(ws_c + QF_OFF);
    const s16x8* KFv  = (const s16x8*)(ws_c + KF_OFF);
    const s16x8* VFv  = (const s16x8*)(ws_c + VF_OFF);
    const s16x8* WoFv = (const s16x8*)(ws_c + WoF_OFF);

    const s16x8 bq0 = QFv[(size_t)(h*128 + bx*2 + 0)*64 + l];
    const s16x8 bq1 = QFv[(size_t)(h*128 + bx*2 + 1)*64 + l];

    f32x4 o0 = {0.f,0.f,0.f,0.f}, o1 = {0.f,0.f,0.f,0.f};
    float mrun = -3.4e38f, srun = 0.f;

    for (int by = 0; by < 8; by++){
        // scores S^T for 8 m-tiles (K=64: real dims + bias dims)
        f32x4 sc[8];
        #pragma unroll
        for (int tt = 0; tt < 8; tt++){
            const int mt = by*8 + tt;
            const s16x8 ak0 = KFv[(size_t)(h*128 + mt*2 + 0)*64 + l];
            const s16x8 ak1 = KFv[(size_t)(h*128 + mt*2 + 1)*64 + l];
            f32x4 c = {0.f,0.f,0.f,0.f};
            c = __builtin_amdgcn_mfma_f32_16x16x32_bf16(ak0, bq0, c, 0, 0, 0);
            c = __builtin_amdgcn_mfma_f32_16x16x32_bf16(ak1, bq1, c, 0, 0, 0);
            sc[tt] = c;
        }
        // chunk max per n (col): in-lane + lanes l^16, l^32
        float cmx = -3.4e38f;
        #pragma unroll
        for (int tt = 0; tt < 8; tt++)
            #pragma unroll
            for (int r = 0; r < 4; r++) cmx = fmaxf(cmx, sc[tt][r]);
        cmx = fmaxf(cmx, __shfl_xor(cmx, 16, 64));
        cmx = fmaxf(cmx, __shfl_xor(cmx, 32, 64));

        const float mnew  = fmaxf(mrun, cmx);
        const float scale = __builtin_amdgcn_exp2f((mrun - mnew)*LOG2E);
        mrun = mnew;
        float csum = 0.f;
        #pragma unroll
        for (int tt = 0; tt < 8; tt++)
            #pragma unroll
            for (int r = 0; r < 4; r++){
                const float e = __builtin_amdgcn_exp2f((sc[tt][r] - mrun)*LOG2E);
                sc[tt][r] = e;
                csum += e;
            }
        csum += __shfl_xor(csum, 16, 64);
        csum += __shfl_xor(csum, 32, 64);
        srun = srun*scale + csum;
        o0 *= scale; o1 *= scale;

        // pack P as PV B-fragments
        s16x8 pb[4];
        #pragma unroll
        for (int s = 0; s < 4; s++){
            s16x8 b;
            #pragma unroll
            for (int r = 0; r < 4; r++){
                b[r]   = f2bfs(sc[2*s][r]);
                b[4+r] = f2bfs(sc[2*s+1][r]);
            }
            pb[s] = b;
        }
        // PV: wave h owns ONLY its head's channels tc = 2h, 2h+1
        #pragma unroll
        for (int s = 0; s < 4; s++){
            const s16x8 av0 = VFv[(size_t)((by*4 + s)*8 + 2*h    )*64 + l];
            const s16x8 av1 = VFv[(size_t)((by*4 + s)*8 + 2*h + 1)*64 + l];
            o0 = __builtin_amdgcn_mfma_f32_16x16x32_bf16(av0, pb[s], o0, 0, 0, 0);
            o1 = __builtin_amdgcn_mfma_f32_16x16x32_bf16(av1, pb[s], o1, 0, 0, 0);
        }
    }

    // normalize and pack AO as Wo B-fragment (k-slice = head h)
    const float inv = __builtin_amdgcn_rcpf(srun);
    s16x8 bao;
    #pragma unroll
    for (int r = 0; r < 4; r++){
        bao[r]   = f2bfs(o0[r]*inv);
        bao[4+r] = f2bfs(o1[r]*inv);
    }
    // Wo partials: wave h covers k in [32h, 32h+32)
    #pragma unroll
    for (int ot = 0; ot < 8; ot++){
        const s16x8 aw = WoFv[(size_t)(ot*4 + h)*64 + l];
        f32x4 po = {0.f,0.f,0.f,0.f};
        po = __builtin_amdgcn_mfma_f32_16x16x32_bf16(aw, bao, po, 0, 0, 0);
        *(f32x4*)&red[((h*8 + ot)*64 + l)*4] = po;
    }
    __syncthreads();

    // reduce over the 4 k-slices; wave h handles ot = 2h, 2h+1
    #pragma unroll
    for (int q = 0; q < 2; q++){
        const int ot = h*2 + q;
        f32x4 s = *(f32x4*)&red[((0*8 + ot)*64 + l)*4];
        #pragma unroll
        for (int hh = 1; hh < 4; hh++)
            s += *(f32x4*)&red[((hh*8 + ot)*64 + l)*4];
        #pragma unroll
        for (int r = 0; r < 4; r++)
            lds2[col*128 + ot*16 + g*4 + r] = s[r];
    }
    __syncthreads();

    // bias + residual; keep in regs and in LDS for stats
    const int c = t & 127, ng = t >> 7;
    float accv[8];
    {
        const float bov = bo[c];
        #pragma unroll
        for (int i = 0; i < 8; i++){
            const int nn = ng*8 + i;
            accv[i] = lds2[nn*128 + c] + bov + x[(size_t)c*1024 + n0 + nn];
            lds2[nn*128 + c] = accv[i];
        }
    }
    __syncthreads();

    // LN stats: wave h owns rows 4h..4h+3
    for (int r = h*4; r < h*4 + 4; r++){
        const float v0 = lds2[r*128 + l];
        const float v1 = lds2[r*128 + 64 + l];
        const float s = wave_sum64(v0 + v1);
        const float q = wave_sum64(fmaf(v0, v0, v1*v1));
        if (l == 0){
            const float mu  = s * 0.0078125f;
            const float var = q * 0.0078125f - mu*mu;
            stats[r]      = mu;
            stats[16 + r] = rsqrtf(var + 1e-5f);
        }
    }
    __syncthreads();

    const float gm = gamma[c], bt = beta[c];
    float4 w0, w1;
    {
        float tmp[8];
        #pragma unroll
        for (int i = 0; i < 8; i++){
            const int nn = ng*8 + i;
            tmp[i] = (accv[i] - stats[nn]) * stats[16 + nn] * gm + bt;
        }
        w0 = make_float4(tmp[0], tmp[1], tmp[2], tmp[3]);
        w1 = make_float4(tmp[4], tmp[5], tmp[6], tmp[7]);
    }
    float4* dst = (float4*)&out[(size_t)c*1024 + n0 + ng*8];
    dst[0] = w0;
    dst[1] = w1;
}

extern "C" void kernel_launch(void* const* d_in, const int* in_sizes, int n_in,
                              void* d_out, int out_size, void* d_ws, size_t ws_size,
                              hipStream_t stream)
{
    const float* x     = (const float*)d_in[0];
    const float* xyz   = (const float*)d_in[1];
    const float* Wq    = (const float*)d_in[2];
    const float* Wk    = (const float*)d_in[3];
    const float* Wv    = (const float*)d_in[4];
    const float* Wp1   = (const float*)d_in[5];
    const float* bp1   = (const float*)d_in[6];
    const float* Wp2   = (const float*)d_in[7];
    const float* bp2   = (const float*)d_in[8];
    const float* Wo    = (const float*)d_in[9];
    const float* bo    = (const float*)d_in[10];
    const float* gamma = (const float*)d_in[11];
    const float* beta  = (const float*)d_in[12];
    float* ws  = (float*)d_ws;
    float* out = (float*)d_out;

    hipLaunchKernelGGL(k_prep,  dim3(64, 4), dim3(256), 0, stream,
                       x, xyz, Wq, Wk, Wv, Wp1, bp1, Wp2, bp2, Wo, ws);
    hipLaunchKernelGGL(k_fused, dim3(64),    dim3(256), 0, stream,
                       bo, x, gamma, beta, ws, out);
}

// Round 7
// 30.900 us; speedup vs baseline: 1.3755x; 1.3755x over previous
//
#include <hip/hip_runtime.h>
#include <hip/hip_bf16.h>

#define LOG2E 1.44269504088896340736f
#define C2G   0.39894228040143267794f   // 1/sqrt(2*pi)
#define K2M  -0.79788456080286535588f   // -2*C2G

typedef __attribute__((ext_vector_type(4))) float f32x4;
typedef __attribute__((ext_vector_type(8))) short s16x8;
typedef __attribute__((ext_vector_type(4))) short s16x4;

// ---------------- workspace layout (float offsets) ----------------
static constexpr size_t QF_OFF   = 0;        // [4h][64nt][2s][64l][8j] bf16 = 262144 sh
static constexpr size_t KF_OFF   = 131072;   // same shape (m-tiles)
static constexpr size_t VF_OFF   = 262144;   // [32ks][8tc][64l][8j] bf16 = 131072 sh
static constexpr size_t PACC_OFF = 327680;   // [8 chunk][1024 n][128 c] fp32
static constexpr size_t PMAX_OFF = 1376256;  // [8][4][1024]
static constexpr size_t PSUM_OFF = 1409024;  // [8][4][1024]
// total = 1,441,792 floats = 5.5 MB

__device__ __forceinline__ short f2bfs(float f){
    __hip_bfloat16 h = __float2bfloat16(f);
    return __builtin_bit_cast(short, h);
}

__device__ __forceinline__ float wave_sum64(float v){
    #pragma unroll
    for (int m = 32; m >= 1; m >>= 1) v += __shfl_xor(v, m, 64);
    return v;
}

// ---------------- kernel 1: projections + pos terms -> bf16 fragments ----
// grid (64, 4): x = n-tile of 16, y = mat (0=Q,1=K,2=V,3=pos terms)
// Fragment k-bijections (A and B use the SAME map; validated on HW R5/R6):
//   scores g(l,j) = (l>>4)*8 + j            (K=64 over 2 slots)
//   PV     f(l,j) = (l>>4)*4 + (j&3) + 16*(j>>2)
__global__ __launch_bounds__(256) void k_prep(
    const float* __restrict__ x, const float* __restrict__ xyz,
    const float* __restrict__ Wq, const float* __restrict__ Wk,
    const float* __restrict__ Wv, const float* __restrict__ Wp1,
    const float* __restrict__ bp1, const float* __restrict__ Wp2,
    const float* __restrict__ bp2, float* __restrict__ ws)
{
    __shared__ float wlds[128*129];   // W [c][k] pitch 129 (mat3: scratch)
    __shared__ float xlds[128*16];    // x [k][n16]
    __shared__ float stage[128*17];   // output tile [c][n] pitch 17 (mat3: p-tile)
    const int t   = threadIdx.x;
    const int mat = blockIdx.y;
    const int bx  = blockIdx.x;
    const int n0  = bx * 16;
    const int l = t & 63, wv_ = t >> 6, g = l >> 4, col = l & 15;

    if (mat == 3){
        float* wb   = wlds;           // [4][128]
        float* Msh  = wlds + 512;     // [4][9]
        float* bbar = wlds + 548;     // [4]
        float* kg   = wlds + 552;     // [4][3][16]  K2M*(M_h·xyz[n])
        float* rowt = wlds + 744;     // [4][16]
        float* colt = wlds + 808;     // [4][16]
        float* pt   = stage;          // [128][17]

        for (int idx = t; idx < 512; idx += 256){
            const int h = idx >> 7, c = idx & 127;
            float s = 0.f;
            #pragma unroll 8
            for (int d = 0; d < 32; d++) s += Wp2[(size_t)(h*32+d)*128 + c];
            wb[idx] = s * 0.03125f;
        }
        if (t < 4){
            float s = 0.f;
            #pragma unroll 8
            for (int d = 0; d < 32; d++) s += bp2[t*32+d];
            bbar[t] = s * 0.03125f;
        }
        {   // p-tile
            const int c = t & 127, ng = t >> 7;
            const float w0 = Wp1[c*3], w1 = Wp1[c*3+1], w2 = Wp1[c*3+2];
            #pragma unroll
            for (int i = 0; i < 8; i++){
                const int nn = ng*8 + i, n = n0 + nn;
                pt[c*17 + nn] = w0*xyz[n*3] + w1*xyz[n*3+1] + w2*xyz[n*3+2];
            }
        }
        __syncthreads();

        if (t < 36){   // M_h[a][b] = sum_c wbar * Wp1[c,a] * Wp1[c,b]
            const int h = t / 9, ab = t % 9, a = ab / 3, b = ab % 3;
            float m = 0.f;
            for (int c = 0; c < 128; c++)
                m += wb[h*128+c] * Wp1[c*3+a] * Wp1[c*3+b];
            Msh[t] = m;
        }
        __syncthreads();

        if (t < 64){   // ROWT / COLT
            const int h = t >> 4, nn = t & 15;
            float ra = 0.f, ca = 0.f;
            for (int c = 0; c < 128; c++){
                const float w  = wb[h*128+c];
                const float p  = pt[c*17+nn];
                const float b1 = bp1[c];
                const float a  = fmaf(2.f*C2G, b1, 0.5f);
                const float p2 = C2G*p*p;
                ra += w * (a*p + p2 + 0.5f*b1 + C2G*b1*b1);
                ca += w * (p2 - a*p);
            }
            rowt[h*16+nn] = ra + bbar[h];
            colt[h*16+nn] = ca;
        } else if (t < 64 + 192){   // kg[h][a][nn]
            const int u = t - 64;
            const int nn = u & 15, ha = u >> 4, h = ha / 3, a = ha % 3;
            const int n = n0 + nn;
            const float gv = Msh[h*9+a*3+0]*xyz[n*3+0]
                           + Msh[h*9+a*3+1]*xyz[n*3+1]
                           + Msh[h*9+a*3+2]*xyz[n*3+2];
            kg[(h*3+a)*16 + nn] = K2M * gv;
        }
        __syncthreads();

        // emit bias fragments (s=1) for QF and KF: 8 slots, 2 per wave
        for (int sl = wv_; sl < 8; sl += 4){
            const bool isQ = sl < 4;
            const int  h   = sl & 3;
            s16x8 v;
            #pragma unroll
            for (int j = 0; j < 8; j++){
                const int dd = g*8 + j;
                float f;
                if (isQ)
                    f = (dd < 3)  ? kg[(h*3+dd)*16 + col]
                      : (dd == 3) ? rowt[h*16 + col]
                      : (dd == 4) ? 1.0f : 0.0f;
                else
                    f = (dd < 3)  ? xyz[(size_t)(n0+col)*3 + dd]
                      : (dd == 3) ? 1.0f
                      : (dd == 4) ? colt[h*16 + col] : 0.0f;
                v[j] = f2bfs(f);
            }
            ((s16x8*)(ws + (isQ ? QF_OFF : KF_OFF)))[(size_t)(h*128 + bx*2 + 1)*64 + l] = v;
        }
        return;
    }

    // ---- mats 0..2: GEMM tile + fragment emit ----
    const float* W = (mat == 0) ? Wq : (mat == 1 ? Wk : Wv);
    for (int i = t; i < 16384; i += 256)
        wlds[(i>>7)*129 + (i&127)] = W[i];
    for (int i = t; i < 2048; i += 256)
        xlds[i] = x[(size_t)(i>>4)*1024 + n0 + (i&15)];
    __syncthreads();

    const int c = t & 127, ng = t >> 7;
    float acc[8] = {0,0,0,0,0,0,0,0};
    #pragma unroll 4
    for (int k = 0; k < 128; k++){
        const float wv = wlds[c*129 + k];
        const float4 a0 = *(const float4*)&xlds[k*16 + ng*8];
        const float4 a1 = *(const float4*)&xlds[k*16 + ng*8 + 4];
        acc[0] = fmaf(wv, a0.x, acc[0]);
        acc[1] = fmaf(wv, a0.y, acc[1]);
        acc[2] = fmaf(wv, a0.z, acc[2]);
        acc[3] = fmaf(wv, a0.w, acc[3]);
        acc[4] = fmaf(wv, a1.x, acc[4]);
        acc[5] = fmaf(wv, a1.y, acc[5]);
        acc[6] = fmaf(wv, a1.z, acc[6]);
        acc[7] = fmaf(wv, a1.w, acc[7]);
    }
    const float qs = (mat == 0) ? 0.17677669529663689f : 1.0f;  // 1/sqrt(32)
    #pragma unroll
    for (int i = 0; i < 8; i++)
        stage[c*17 + ng*8 + i] = acc[i] * qs;
    __syncthreads();

    if (mat != 2){   // Q/K s=0 fragment: wave = head
        const int h = wv_;
        s16x8 v;
        #pragma unroll
        for (int j = 0; j < 8; j++)
            v[j] = f2bfs(stage[(h*32 + g*8 + j)*17 + col]);
        ((s16x8*)(ws + (mat == 0 ? QF_OFF : KF_OFF)))[(size_t)(h*128 + bx*2 + 0)*64 + l] = v;
    } else {         // V half-fragments: this block is m-tile bx
        #pragma unroll
        for (int q = 0; q < 2; q++){
            const int tc = wv_*2 + q;
            s16x4 hv;
            #pragma unroll
            for (int jj = 0; jj < 4; jj++)
                hv[jj] = f2bfs(stage[(tc*16 + col)*17 + g*4 + jj]);
            ((s16x4*)(ws + VF_OFF))[(((size_t)(bx>>1)*8 + tc)*64 + l)*2 + (bx & 1)] = hv;
        }
    }
}

// ---------------- kernel 2: MFMA scores + chunk softmax + MFMA PV --------
// grid (64, 8): x = n-tile of 16, y = m-chunk of 128. block 256 = 4 waves,
// wave = head. No LDS. Wave h computes PV ONLY for its head's channels
// tc = 2h, 2h+1 (race-free, no redundant work).
__global__ __launch_bounds__(256) void k_attn(
    const float* __restrict__ ws_c, float* __restrict__ ws)
{
    const int t = threadIdx.x, l = t & 63, h = t >> 6;
    const int bx = blockIdx.x, by = blockIdx.y;
    const int g = l >> 4;

    const s16x8* QFv = (const s16x8*)(ws_c + QF_OFF);
    const s16x8* KFv = (const s16x8*)(ws_c + KF_OFF);
    const s16x8* VFv = (const s16x8*)(ws_c + VF_OFF);

    const s16x8 bq0 = QFv[(size_t)(h*128 + bx*2 + 0)*64 + l];
    const s16x8 bq1 = QFv[(size_t)(h*128 + bx*2 + 1)*64 + l];

    // scores S^T for 8 m-tiles (K=64: real dims + bias dims)
    f32x4 sc[8];
    #pragma unroll
    for (int tt = 0; tt < 8; tt++){
        const int mt = by*8 + tt;
        const s16x8 ak0 = KFv[(size_t)(h*128 + mt*2 + 0)*64 + l];
        const s16x8 ak1 = KFv[(size_t)(h*128 + mt*2 + 1)*64 + l];
        f32x4 c = {0.f,0.f,0.f,0.f};
        c = __builtin_amdgcn_mfma_f32_16x16x32_bf16(ak0, bq0, c, 0, 0, 0);
        c = __builtin_amdgcn_mfma_f32_16x16x32_bf16(ak1, bq1, c, 0, 0, 0);
        sc[tt] = c;
    }

    // chunk softmax over m (in-lane 32 + lanes l^16, l^32)
    float mx = -3.4e38f;
    #pragma unroll
    for (int tt = 0; tt < 8; tt++)
        #pragma unroll
        for (int r = 0; r < 4; r++) mx = fmaxf(mx, sc[tt][r]);
    mx = fmaxf(mx, __shfl_xor(mx, 16, 64));
    mx = fmaxf(mx, __shfl_xor(mx, 32, 64));

    float sum = 0.f;
    #pragma unroll
    for (int tt = 0; tt < 8; tt++)
        #pragma unroll
        for (int r = 0; r < 4; r++){
            const float e = __builtin_amdgcn_exp2f((sc[tt][r] - mx)*LOG2E);
            sc[tt][r] = e;
            sum += e;
        }
    sum += __shfl_xor(sum, 16, 64);
    sum += __shfl_xor(sum, 32, 64);

    if (l < 16){
        ws[PMAX_OFF + (size_t)(by*4 + h)*1024 + bx*16 + l] = mx;
        ws[PSUM_OFF + (size_t)(by*4 + h)*1024 + bx*16 + l] = sum;
    }

    // pack P as PV B-fragments: step s uses tiles {2s, 2s+1}, regs 0..3
    s16x8 pb[4];
    #pragma unroll
    for (int s = 0; s < 4; s++){
        s16x8 b;
        #pragma unroll
        for (int r = 0; r < 4; r++){
            b[r]   = f2bfs(sc[2*s][r]);
            b[4+r] = f2bfs(sc[2*s+1][r]);
        }
        pb[s] = b;
    }

    // PV: wave h owns tc = 2h, 2h+1 only
    f32x4 o0 = {0.f,0.f,0.f,0.f}, o1 = {0.f,0.f,0.f,0.f};
    #pragma unroll
    for (int s = 0; s < 4; s++){
        const s16x8 av0 = VFv[(size_t)((by*4 + s)*8 + 2*h    )*64 + l];
        const s16x8 av1 = VFv[(size_t)((by*4 + s)*8 + 2*h + 1)*64 + l];
        o0 = __builtin_amdgcn_mfma_f32_16x16x32_bf16(av0, pb[s], o0, 0, 0, 0);
        o1 = __builtin_amdgcn_mfma_f32_16x16x32_bf16(av1, pb[s], o1, 0, 0, 0);
    }
    // D layout: c = tc*16 + g*4 + r, n = l&15
    const size_t base = PACC_OFF + (size_t)(by*1024 + bx*16 + (l & 15))*128;
    *(f32x4*)&ws[base + (2*h    )*16 + g*4] = o0;
    *(f32x4*)&ws[base + (2*h + 1)*16 + g*4] = o1;
}

// ---------------- kernel 3: combine + Wo matmul + residual + LayerNorm ---
// grid (256): n-tile of 4. block 256.
__global__ __launch_bounds__(256) void k_final(
    const float* __restrict__ Wo, const float* __restrict__ bo,
    const float* __restrict__ x, const float* __restrict__ gamma,
    const float* __restrict__ beta, const float* __restrict__ ws,
    float* __restrict__ out)
{
    __shared__ float wlds[128*129];
    __shared__ float alds[128*4];     // [k][nn] then reused as [nn][c]
    __shared__ float wcomb[8*16];     // [chunk][h*4+nn]
    __shared__ float stats[8];        // mu[4], rstd[4]
    const int t  = threadIdx.x;
    const int n0 = blockIdx.x * 4;

    for (int i = t; i < 4096; i += 256){
        const float4 wv = *(const float4*)(Wo + (size_t)i*4);
        const int cc = (i*4) >> 7, kk = (i*4) & 127;
        wlds[cc*129 + kk + 0] = wv.x;
        wlds[cc*129 + kk + 1] = wv.y;
        wlds[cc*129 + kk + 2] = wv.z;
        wlds[cc*129 + kk + 3] = wv.w;
    }
    if (t < 16){   // combine weights per (h, nn)
        const int h = t >> 2, nn = t & 3;
        float pm[8]; float mx = -3.4e38f;
        #pragma unroll
        for (int k = 0; k < 8; k++){
            pm[k] = ws[PMAX_OFF + (size_t)(k*4 + h)*1024 + n0 + nn];
            mx = fmaxf(mx, pm[k]);
        }
        float lam[8]; float den = 0.f;
        #pragma unroll
        for (int k = 0; k < 8; k++){
            lam[k] = __builtin_amdgcn_exp2f((pm[k] - mx)*LOG2E);
            den = fmaf(lam[k], ws[PSUM_OFF + (size_t)(k*4 + h)*1024 + n0 + nn], den);
        }
        const float rd = __builtin_amdgcn_rcpf(den);
        #pragma unroll
        for (int k = 0; k < 8; k++) wcomb[k*16 + t] = lam[k]*rd;
    }
    __syncthreads();

    const int c = t & 127, ng = t >> 7, h = c >> 5;
    {   // combine PACC -> alds[k-channel][nn]
        #pragma unroll
        for (int j = 0; j < 2; j++){
            const int nn = ng*2 + j;
            float num = 0.f;
            #pragma unroll
            for (int k = 0; k < 8; k++)
                num = fmaf(wcomb[k*16 + h*4 + nn],
                           ws[PACC_OFF + (size_t)(k*1024 + n0 + nn)*128 + c], num);
            alds[c*4 + nn] = num;
        }
    }
    __syncthreads();

    float acc2[2] = {0.f, 0.f};
    #pragma unroll 4
    for (int k = 0; k < 128; k++){
        const float  wv = wlds[c*129 + k];
        const float2 a2 = *(const float2*)&alds[k*4 + ng*2];
        acc2[0] = fmaf(wv, a2.x, acc2[0]);
        acc2[1] = fmaf(wv, a2.y, acc2[1]);
    }
    const float  bov = bo[c];
    const float2 xr  = *(const float2*)(x + (size_t)c*1024 + n0 + ng*2);
    acc2[0] += bov + xr.x;
    acc2[1] += bov + xr.y;
    __syncthreads();   // done reading alds

    alds[(ng*2 + 0)*128 + c] = acc2[0];
    alds[(ng*2 + 1)*128 + c] = acc2[1];
    __syncthreads();

    {   // LN stats: wave w owns row w
        const int lane = t & 63, w = t >> 6;
        const float v0 = alds[w*128 + lane];
        const float v1 = alds[w*128 + 64 + lane];
        const float s = wave_sum64(v0 + v1);
        const float q = wave_sum64(fmaf(v0, v0, v1*v1));
        if (lane == 0){
            const float mu  = s * 0.0078125f;
            const float var = q * 0.0078125f - mu*mu;
            stats[w]     = mu;
            stats[4 + w] = rsqrtf(var + 1e-5f);
        }
    }
    __syncthreads();

    const float g = gamma[c], b = beta[c];
    const int nn0 = ng*2;
    float2 o2;
    o2.x = (acc2[0] - stats[nn0])  * stats[4 + nn0]  * g + b;
    o2.y = (acc2[1] - stats[nn0+1])* stats[4 + nn0+1]* g + b;
    *(float2*)(out + (size_t)c*1024 + n0 + nn0) = o2;
}

extern "C" void kernel_launch(void* const* d_in, const int* in_sizes, int n_in,
                              void* d_out, int out_size, void* d_ws, size_t ws_size,
                              hipStream_t stream)
{
    const float* x     = (const float*)d_in[0];
    const float* xyz   = (const float*)d_in[1];
    const float* Wq    = (const float*)d_in[2];
    const float* Wk    = (const float*)d_in[3];
    const float* Wv    = (const float*)d_in[4];
    const float* Wp1   = (const float*)d_in[5];
    const float* bp1   = (const float*)d_in[6];
    const float* Wp2   = (const float*)d_in[7];
    const float* bp2   = (const float*)d_in[8];
    const float* Wo    = (const float*)d_in[9];
    const float* bo    = (const float*)d_in[10];
    const float* gamma = (const float*)d_in[11];
    const float* beta  = (const float*)d_in[12];
    float* ws  = (float*)d_ws;
    float* out = (float*)d_out;

    hipLaunchKernelGGL(k_prep,  dim3(64, 4), dim3(256), 0, stream,
                       x, xyz, Wq, Wk, Wv, Wp1, bp1, Wp2, bp2, ws);
    hipLaunchKernelGGL(k_attn,  dim3(64, 8), dim3(256), 0, stream, ws, ws);
    hipLaunchKernelGGL(k_final, dim3(256),   dim3(256), 0, stream,
                       Wo, bo, x, gamma, beta, ws, out);
}